// Round 6
// baseline (1493.483 us; speedup 1.0000x reference)
//
#include <hip/hip_runtime.h>
#include <hip/hip_bf16.h>

#define LL 12
#define BB 32
#define SS 197
#define DV 768
#define DD 512
#define CC 48
#define VV 49
#define LOSS_DEN 786432.0f

typedef unsigned short u16;
typedef unsigned int u32;
using bf16x8 = __attribute__((ext_vector_type(8))) __bf16;
using f32x4 = __attribute__((ext_vector_type(4))) float;
using u16x8 = __attribute__((ext_vector_type(8))) u16;

__device__ __forceinline__ u16 bf16h(float x) {
    u32 u = __builtin_bit_cast(u32, x);
    return (u16)((u + 0x7FFFu + ((u >> 16) & 1u)) >> 16);
}
__device__ __forceinline__ float bf2f(u16 h) {
    u32 u = ((u32)h) << 16;
    return __builtin_bit_cast(float, u);
}
__device__ __forceinline__ f32x4 mfma16(bf16x8 a, bf16x8 b, f32x4 c) {
    return __builtin_amdgcn_mfma_f32_16x16x32_bf16(a, b, c, 0, 0, 0);
}
__device__ __forceinline__ void gl_lds16(const void* g, void* s) {
    __builtin_amdgcn_global_load_lds((const __attribute__((address_space(1))) u32*)g,
                                     (__attribute__((address_space(3))) u32*)s, 16, 0, 0);
}

// ---------------------------------------------------------------------------
// Pool + bf16 hi/lo split of X
__global__ __launch_bounds__(256) void pool_split(const float* __restrict__ feats,
                                                  u16* __restrict__ Xh, u16* __restrict__ Xl) {
    int row = blockIdx.x;
    int t = threadIdx.x;
    int v = row % VV;
    int lb = row / VV;
    const float* f = feats + (size_t)lb * SS * DV;
    for (int d = t; d < DV; d += 256) {
        float val;
        if (v == 0) {
            val = f[d];
        } else {
            int i = v - 1;
            int s = (i * 196) / 48;
            int e = ((i + 1) * 196 + 47) / 48;
            float acc = 0.0f;
            for (int j = s; j < e; ++j) acc += f[(size_t)(1 + j) * DV + d];
            val = acc / (float)(e - s);
        }
        u16 h = bf16h(val);
        Xh[(size_t)row * DV + d] = h;
        Xl[(size_t)row * DV + d] = bf16h(val - bf2f(h));
    }
}

// Combined weight splits
#define NLW (512 * 768)
#define NGW (512 * 1536)
#define NUW (512 * 1024)
__global__ __launch_bounds__(256) void wsplit_all(const float* __restrict__ Wl,
                                                  const float* __restrict__ Wg,
                                                  const float* __restrict__ Wu,
                                                  u16* Wlh, u16* Wll, u16* Wgh, u16* Wgl,
                                                  u16* Wuh, u16* Wul) {
    int i = blockIdx.x * 256 + threadIdx.x;
    float v;
    u16 *ph, *pl;
    int j;
    if (i < NLW) { v = Wl[i]; ph = Wlh; pl = Wll; j = i; }
    else if (i < NLW + NGW) { j = i - NLW; v = Wg[j]; ph = Wgh; pl = Wgl; }
    else { j = i - NLW - NGW; v = Wu[j]; ph = Wuh; pl = Wul; }
    u16 hh = bf16h(v);
    ph[j] = hh;
    pl[j] = bf16h(v - bf2f(hh));
}

// ---------------------------------------------------------------------------
// Generic f32 GEMM: C[m,n] = sum_k A[m,k]*W[n*wstride+k] + bias[n]; C stride 512.
__global__ __launch_bounds__(256) void gemm_f32(const float* __restrict__ A, int lda,
                                                const float* __restrict__ W, int wstride, int K,
                                                const float* __restrict__ bias,
                                                float* __restrict__ Cout) {
    __shared__ float As[32][65];
    __shared__ float Bs[32][65];
    int t = threadIdx.x;
    int m0 = blockIdx.x * 64;
    int n0 = blockIdx.y * 64;
    int r = t >> 2;
    int kc = (t & 3) * 8;
    int tx = t & 15, ty = t >> 4;
    float acc[4][4] = {};
    for (int k0 = 0; k0 < K; k0 += 32) {
        const float4* pa = (const float4*)(A + (size_t)(m0 + r) * lda + k0 + kc);
        float4 a0 = pa[0], a1 = pa[1];
        const float4* pw = (const float4*)(W + (size_t)(n0 + r) * wstride + k0 + kc);
        float4 w0 = pw[0], w1 = pw[1];
        As[kc + 0][r] = a0.x; As[kc + 1][r] = a0.y; As[kc + 2][r] = a0.z; As[kc + 3][r] = a0.w;
        As[kc + 4][r] = a1.x; As[kc + 5][r] = a1.y; As[kc + 6][r] = a1.z; As[kc + 7][r] = a1.w;
        Bs[kc + 0][r] = w0.x; Bs[kc + 1][r] = w0.y; Bs[kc + 2][r] = w0.z; Bs[kc + 3][r] = w0.w;
        Bs[kc + 4][r] = w1.x; Bs[kc + 5][r] = w1.y; Bs[kc + 6][r] = w1.z; Bs[kc + 7][r] = w1.w;
        __syncthreads();
#pragma unroll
        for (int kk = 0; kk < 32; ++kk) {
            float a[4], b[4];
#pragma unroll
            for (int i = 0; i < 4; ++i) { a[i] = As[kk][ty * 4 + i]; b[i] = Bs[kk][tx * 4 + i]; }
#pragma unroll
            for (int i = 0; i < 4; ++i)
#pragma unroll
                for (int j = 0; j < 4; ++j) acc[i][j] += a[i] * b[j];
        }
        __syncthreads();
    }
#pragma unroll
    for (int i = 0; i < 4; ++i) {
        int m = m0 + ty * 4 + i;
#pragma unroll
        for (int j = 0; j < 4; ++j) {
            int n = n0 + tx * 4 + j;
            Cout[(size_t)m * DD + n] = acc[i][j] + (bias ? bias[n] : 0.0f);
        }
    }
}

// ---------------------------------------------------------------------------
// vt = X @ W_lin.T + b_lin  (bf16x3 MFMA), emits bf16 hi/lo planes.
__global__ __launch_bounds__(256, 2) void vt_gemm(const u16* __restrict__ Xh, const u16* __restrict__ Xl,
                                                  const u16* __restrict__ Wh, const u16* __restrict__ Wl,
                                                  const float* __restrict__ bias,
                                                  u16* __restrict__ vthp, u16* __restrict__ vtlp) {
    __shared__ u16 sm[24576];
    int tid = threadIdx.x;
    int w = tid >> 6, l = tid & 63, lr = l & 15, ls = l >> 4;
    int m0 = blockIdx.x * 128, n0 = blockIdx.y * 64;
    f32x4 acc[2][4];
#pragma unroll
    for (int i = 0; i < 2; ++i)
#pragma unroll
        for (int j = 0; j < 4; ++j) acc[i][j] = f32x4{0.f, 0.f, 0.f, 0.f};

    auto stage = [&](u16* dst, int k0) {
#pragma unroll
        for (int is = 0; is < 6; ++is) {
            int q = is * 256 + tid;
            const u16* src;
            int off;
            if (is < 2)      { int qr = q;        int row = qr >> 2, sl = qr & 3; src = Xh + (size_t)(m0 + row) * DV + k0 + ((sl ^ ((row >> 1) & 3)) << 3); off = qr * 8; }
            else if (is < 4) { int qr = q - 512;  int row = qr >> 2, sl = qr & 3; src = Xl + (size_t)(m0 + row) * DV + k0 + ((sl ^ ((row >> 1) & 3)) << 3); off = 4096 + qr * 8; }
            else if (is < 5) { int qr = q - 1024; int row = qr >> 2, sl = qr & 3; src = Wh + (size_t)(n0 + row) * DV + k0 + ((sl ^ ((row >> 1) & 3)) << 3); off = 8192 + qr * 8; }
            else             { int qr = q - 1280; int row = qr >> 2, sl = qr & 3; src = Wl + (size_t)(n0 + row) * DV + k0 + ((sl ^ ((row >> 1) & 3)) << 3); off = 10240 + qr * 8; }
            gl_lds16(src, dst + off);
        }
    };

    stage(sm, 0);
    __syncthreads();
    for (int t = 0; t < 24; ++t) {
        u16* cur = sm + ((t & 1) ? 12288 : 0);
        u16* nxt = sm + ((t & 1) ? 0 : 12288);
        if (t + 1 < 24) stage(nxt, (t + 1) * 32);
        bf16x8 ah[2], al2[2], bh[4], bl2[4];
#pragma unroll
        for (int rf = 0; rf < 2; ++rf) {
            int row = 32 * w + 16 * rf + lr;
            int ro = row * 32 + ((ls ^ ((row >> 1) & 3)) << 3);
            ah[rf] = *(const bf16x8*)(cur + ro);
            al2[rf] = *(const bf16x8*)(cur + 4096 + ro);
        }
#pragma unroll
        for (int cf = 0; cf < 4; ++cf) {
            int n = 16 * cf + lr;
            int no = n * 32 + ((ls ^ ((n >> 1) & 3)) << 3);
            bh[cf] = *(const bf16x8*)(cur + 8192 + no);
            bl2[cf] = *(const bf16x8*)(cur + 10240 + no);
        }
#pragma unroll
        for (int rf = 0; rf < 2; ++rf)
#pragma unroll
            for (int cf = 0; cf < 4; ++cf) {
                acc[rf][cf] = mfma16(ah[rf], bh[cf], acc[rf][cf]);
                acc[rf][cf] = mfma16(ah[rf], bl2[cf], acc[rf][cf]);
                acc[rf][cf] = mfma16(al2[rf], bh[cf], acc[rf][cf]);
            }
        __syncthreads();
    }
#pragma unroll
    for (int rf = 0; rf < 2; ++rf)
#pragma unroll
        for (int cf = 0; cf < 4; ++cf)
#pragma unroll
            for (int r = 0; r < 4; ++r) {
                int row = m0 + 32 * w + 16 * rf + 4 * ls + r;
                int col = n0 + 16 * cf + lr;
                float v = acc[rf][cf][r] + bias[col];
                size_t o = (size_t)row * DD + col;
                u16 hh = bf16h(v);
                vthp[o] = hh;
                vtlp[o] = bf16h(v - bf2f(hh));
            }
}

// ---------------------------------------------------------------------------
// Transpose vt planes per (l,b): [49][512] -> [512][64] (v>=49 zero-padded), plain layout.
__global__ __launch_bounds__(256) void vtT_kernel(const u16* __restrict__ vth, const u16* __restrict__ vtl,
                                                  u16* __restrict__ vtTh, u16* __restrict__ vtTl) {
    __shared__ u16 tile[49 * 520];
    int lb = blockIdx.x;
    int tid = threadIdx.x;
    for (int pl = 0; pl < 2; ++pl) {
        const u16* src = (pl ? vtl : vth) + (size_t)lb * VV * DD;
        u16* dst = (pl ? vtTl : vtTh) + (size_t)lb * 512 * 64;
        for (int q = tid; q < VV * 64; q += 256) {
            int r = q >> 6, c = q & 63;
            *(uint4*)(tile + r * 520 + c * 8) = *(const uint4*)(src + (size_t)r * DD + c * 8);
        }
        __syncthreads();
        for (int q = tid; q < 512 * 64; q += 256) {
            int d = q >> 6, v = q & 63;
            dst[q] = (v < VV) ? tile[v * 520 + d] : (u16)0;
        }
        __syncthreads();
    }
}

// ---------------------------------------------------------------------------
__global__ __launch_bounds__(256) void init_q_loss(const float* __restrict__ ce,
                                                   u16* __restrict__ qh, u16* __restrict__ ql,
                                                   float* __restrict__ loss) {
    int i = blockIdx.x * 256 + threadIdx.x;
    float v = ce[i % (CC * DD)];
    u16 hh = bf16h(v);
    qh[i] = hh;
    ql[i] = bf16h(v - bf2f(hh));
    if (i == 0) loss[0] = 0.0f;
}

// ---------------------------------------------------------------------------
// Fused per-layer kernel: attention (QK^T, softmax, PV) + gate/upd + q update.
// Grid: 32 images x 8 n-splits (256 blocks) x 512 threads. last: grid 32, A-C only.
__global__ __launch_bounds__(512, 2) void layer_fused(
    const u16* __restrict__ qhp, const u16* __restrict__ qlp,
    const u16* __restrict__ vthL, const u16* __restrict__ vtlL,
    const u16* __restrict__ vtThL, const u16* __restrict__ vtTlL,
    const u16* __restrict__ Wgh, const u16* __restrict__ Wgl,
    const u16* __restrict__ Wuh, const u16* __restrict__ Wul,
    const float* __restrict__ CgL, const float* __restrict__ bu,
    float* __restrict__ fcur, const float* __restrict__ fprev,
    float* __restrict__ loss, int do_loss, int last,
    u16* __restrict__ qoh, u16* __restrict__ qol) {
    // LDS map (u16 units): STG region [0,22528) multi-use; Sb/P region [22528,29440)
    __shared__ u16 sm[29440];
    float* Sb = (float*)(sm + 22528);  // [48][68] f32 (13056 B)
    u16* Ph = sm + 22528;              // [48][72] (overlays Sb, barrier-separated)
    u16* Pl = sm + 22528 + 3456;
    int tid = threadIdx.x;
    int w = tid >> 6, l = tid & 63, lr = l & 15, ls = l >> 4;
    int b, ns;
    if (last) { b = blockIdx.x; ns = 0; }
    else { b = blockIdx.x >> 3; ns = blockIdx.x & 7; }
    size_t qrow0 = (size_t)b * CC;

    // ---- Phase A: QK^T (S[48][64], K=512) ----
    auto stageA = [&](u16* buf, int k0) {
        if (tid < 384) {
            int p = tid >= 192;
            int t = tid - 192 * p;
            int row = t >> 2, sl = t & 3;
            const u16* src = (p ? qlp : qhp) + (qrow0 + row) * DD + k0 + ((sl ^ ((row >> 1) & 3)) << 3);
            gl_lds16(src, buf + p * 1536 + t * 8);
        }
        {
            int p = tid >= 256;
            int t2 = tid & 255;
            int row = t2 >> 2, sl = t2 & 3;
            int srow = row < VV ? row : VV - 1;
            const u16* src = (p ? vtlL : vthL) + ((size_t)b * VV + srow) * DD + k0 + ((sl ^ ((row >> 1) & 3)) << 3);
            gl_lds16(src, buf + 3072 + p * 2048 + t2 * 8);
        }
    };
    f32x4 acc_s[3];
#pragma unroll
    for (int i = 0; i < 3; ++i) acc_s[i] = f32x4{0.f, 0.f, 0.f, 0.f};
    int c4 = w & 3, wh = w >> 2;
    int rlo = wh ? 2 : 0, rhi = wh ? 3 : 2;
    stageA(sm, 0);
    __syncthreads();
    for (int t = 0; t < 16; ++t) {
        u16* cur = sm + (t & 1) * 7168;
        if (t + 1 < 16) stageA(sm + ((t + 1) & 1) * 7168, (t + 1) * 32);
        int n = 16 * c4 + lr;
        int no = 3072 + n * 32 + ((ls ^ ((n >> 1) & 3)) << 3);
        bf16x8 vh8 = *(const bf16x8*)(cur + no);
        bf16x8 vl8 = *(const bf16x8*)(cur + 2048 + no);
        for (int rf = rlo; rf < rhi; ++rf) {
            int row = 16 * rf + lr;
            int ao = row * 32 + ((ls ^ ((row >> 1) & 3)) << 3);
            bf16x8 qh8 = *(const bf16x8*)(cur + ao);
            bf16x8 ql8 = *(const bf16x8*)(cur + 1536 + ao);
            acc_s[rf] = mfma16(qh8, vh8, acc_s[rf]);
            acc_s[rf] = mfma16(qh8, vl8, acc_s[rf]);
            acc_s[rf] = mfma16(ql8, vh8, acc_s[rf]);
        }
        __syncthreads();
    }
    for (int rf = rlo; rf < rhi; ++rf)
#pragma unroll
        for (int r = 0; r < 4; ++r)
            Sb[(16 * rf + 4 * ls + r) * 68 + 16 * c4 + lr] = acc_s[rf][r];
    __syncthreads();  // Sb visible; STG reads done

    // ---- PV staging helper (VTT overlays STG at 0, [512 d][32 v] per chunk) ----
    auto stageVt = [&](const u16* basev, int v0) {
#pragma unroll
        for (int i = 0; i < 4; ++i) {
            int idx = i * 512 + tid;
            int d = idx >> 2, vs = idx & 3;
            gl_lds16(basev + ((size_t)b * DD + d) * 64 + v0 + ((vs ^ (d & 3)) << 3), sm + idx * 8);
        }
    };
    stageVt(vtThL, 0);

    // ---- Phase B: softmax (register-staged; P overlays Sb after barrier) ----
    float pvv[13];
    float inv = 0.0f;
    int srow = tid >> 2, sub = tid & 3;
    if (tid < 192) {
        float mx = -3e38f;
#pragma unroll
        for (int j = 0; j < 13; ++j) {
            int c = sub + 4 * j;
            float v = (c < VV) ? Sb[srow * 68 + c] : -3e38f;
            pvv[j] = v;
            mx = fmaxf(mx, v);
        }
        mx = fmaxf(mx, __shfl_xor(mx, 1));
        mx = fmaxf(mx, __shfl_xor(mx, 2));
        float s = 0.0f;
#pragma unroll
        for (int j = 0; j < 13; ++j) {
            pvv[j] = __expf(pvv[j] - mx);
            s += pvv[j];
        }
        s += __shfl_xor(s, 1);
        s += __shfl_xor(s, 2);
        inv = 1.0f / s;
    }
    __syncthreads();  // all Sb reads done; stageVt drained
    if (tid < 192) {
#pragma unroll
        for (int j = 0; j < 13; ++j) {
            int c = sub + 4 * j;
            if (c < 64) {
                u16 hh = 0, hl = 0;
                if (c < VV) {
                    float p = pvv[j] * inv;
                    hh = bf16h(p);
                    hl = bf16h(p - bf2f(hh));
                }
                Ph[srow * 72 + c] = hh;
                Pl[srow * 72 + c] = hl;
            }
        }
        // cols covered: sub+4j for j<13 -> up to 48+sub; fill remaining cols < 64
#pragma unroll
        for (int j = 13; j < 16; ++j) {
            int c = sub + 4 * j;
            if (c < 64) { Ph[srow * 72 + c] = 0; Pl[srow * 72 + c] = 0; }
        }
    }
    __syncthreads();  // P visible; VTT(vh,v0=0) staged

    // ---- Phase C: PV (fuse[48][512] in regs; x3) ----
    f32x4 acc_f[3][4];
#pragma unroll
    for (int i = 0; i < 3; ++i)
#pragma unroll
        for (int j = 0; j < 4; ++j) acc_f[i][j] = f32x4{0.f, 0.f, 0.f, 0.f};
    auto pvPass = [&](const u16* Pp, int v0) {
        bf16x8 av[3];
#pragma unroll
        for (int rf = 0; rf < 3; ++rf)
            av[rf] = *(const bf16x8*)(Pp + (16 * rf + lr) * 72 + v0 + ls * 8);
#pragma unroll
        for (int cf = 0; cf < 4; ++cf) {
            int d = (w << 6) + (cf << 4) + lr;
            bf16x8 bv = *(const bf16x8*)(sm + d * 32 + ((ls ^ (d & 3)) << 3));
#pragma unroll
            for (int rf = 0; rf < 3; ++rf) acc_f[rf][cf] = mfma16(av[rf], bv, acc_f[rf][cf]);
        }
    };
    pvPass(Ph, 0); pvPass(Pl, 0);
    __syncthreads();
    stageVt(vtTlL, 0);
    __syncthreads();
    pvPass(Ph, 0);
    __syncthreads();
    stageVt(vtThL, 32);
    __syncthreads();
    pvPass(Ph, 32); pvPass(Pl, 32);
    __syncthreads();
    stageVt(vtTlL, 32);
    __syncthreads();
    pvPass(Ph, 32);

    // ---- fuse f32 write + loss (n-split 0 blocks only) ----
    if (ns == 0) {
        float d2 = 0.0f;
#pragma unroll
        for (int rf = 0; rf < 3; ++rf)
#pragma unroll
            for (int cf = 0; cf < 4; ++cf)
#pragma unroll
                for (int r = 0; r < 4; ++r) {
                    int row = 16 * rf + 4 * ls + r;
                    int col = (w << 6) + (cf << 4) + lr;
                    float f = acc_f[rf][cf][r];
                    size_t o = (qrow0 + row) * DD + col;
                    fcur[o] = f;
                    if (do_loss) { float d = f - fprev[o]; d2 += d * d; }
                }
        if (do_loss) {
#pragma unroll
            for (int off = 32; off > 0; off >>= 1) d2 += __shfl_xor(d2, off);
            if (l == 0) atomicAdd(loss, d2);
        }
    }
    if (last) return;

    // ---- Phase D: gate/upd fuse-part, 8 k-chunks of 64 through LDS ----
    // STG map for D: FCH 0, FCL 3072, WG_H 6144, WG_L 10240, WU_H 14336, WU_L 18432
    f32x4 accg[2], accu[2];
#pragma unroll
    for (int i = 0; i < 2; ++i) { accg[i] = f32x4{0.f, 0.f, 0.f, 0.f}; accu[i] = f32x4{0.f, 0.f, 0.f, 0.f}; }
    int cfD = w & 3, rhD = w >> 2;
    int rf0 = rhD ? 2 : 0, nrf = rhD ? 1 : 2;
    int nloc = cfD * 16 + lr;
    int nglob = ns * 64;
    for (int c = 0; c < 8; ++c) {
        __syncthreads();  // prior chunk (or PV) LDS reads complete
        if (w == c) {
#pragma unroll
            for (int rf = 0; rf < 3; ++rf)
#pragma unroll
                for (int cf = 0; cf < 4; ++cf)
#pragma unroll
                    for (int r = 0; r < 4; ++r) {
                        int row = 16 * rf + 4 * ls + r;
                        int col = cf * 16 + lr;
                        float f = acc_f[rf][cf][r];
                        u16 hh = bf16h(f);
                        int ad = row * 64 + (((col >> 3) ^ (row & 7)) << 3) + (col & 7);
                        sm[ad] = hh;
                        sm[3072 + ad] = bf16h(f - bf2f(hh));
                    }
        }
        {
            int rown = tid >> 3, sl = tid & 7;
            int koff = c * 64 + ((sl ^ (rown & 7)) << 3);
            size_t gro = (size_t)(nglob + rown);
            gl_lds16(Wgh + gro * 1536 + koff, sm + 6144 + tid * 8);
            gl_lds16(Wgl + gro * 1536 + koff, sm + 10240 + tid * 8);
            gl_lds16(Wuh + gro * 1024 + koff, sm + 14336 + tid * 8);
            gl_lds16(Wul + gro * 1024 + koff, sm + 18432 + tid * 8);
        }
        __syncthreads();
#pragma unroll
        for (int ks = 0; ks < 2; ++ks) {
            int slB = ks * 4 + ls;
            int bo = nloc * 64 + ((slB ^ (nloc & 7)) << 3);
            bf16x8 gh8 = *(const bf16x8*)(sm + 6144 + bo);
            bf16x8 gl8 = *(const bf16x8*)(sm + 10240 + bo);
            bf16x8 uh8 = *(const bf16x8*)(sm + 14336 + bo);
            bf16x8 ul8 = *(const bf16x8*)(sm + 18432 + bo);
            for (int i = 0; i < nrf; ++i) {
                int row = 16 * (rf0 + i) + lr;
                int ao = row * 64 + ((slB ^ (row & 7)) << 3);
                bf16x8 fh8 = *(const bf16x8*)(sm + ao);
                bf16x8 fl8 = *(const bf16x8*)(sm + 3072 + ao);
                accg[i] = mfma16(fh8, gh8, accg[i]);
                accg[i] = mfma16(fh8, gl8, accg[i]);
                accg[i] = mfma16(fl8, gh8, accg[i]);
                accu[i] = mfma16(fh8, uh8, accu[i]);
                accu[i] = mfma16(fh8, ul8, accu[i]);
                accu[i] = mfma16(fl8, uh8, accu[i]);
            }
        }
    }

    // ---- Phase E: gate/upd q-part (K=512, 16 steps, dbuf) ----
    // buf layout: qh 0, ql 1536, Wg2h 3072, Wg2l 5120, Wu2h 7168, Wu2l 9216 (11264 each)
    auto stageE = [&](u16* buf, int k0) {
        if (tid < 384) {
            int p = tid >= 192;
            int t = tid - 192 * p;
            int row = t >> 2, sl = t & 3;
            const u16* src = (p ? qlp : qhp) + (qrow0 + row) * DD + k0 + ((sl ^ ((row >> 1) & 3)) << 3);
            gl_lds16(src, buf + p * 1536 + t * 8);
        }
#pragma unroll
        for (int a = 0; a < 2; ++a) {
            int idx = tid + a * 512;
            int arr = idx >> 8;
            int t2 = idx & 255;
            int row = t2 >> 2, sl = t2 & 3;
            int ko = k0 + ((sl ^ ((row >> 1) & 3)) << 3);
            size_t gr = (size_t)(nglob + row);
            const u16* src;
            u16* dst;
            if (arr == 0) { src = Wgh + gr * 1536 + 512 + ko; dst = buf + 3072 + t2 * 8; }
            else if (arr == 1) { src = Wgl + gr * 1536 + 512 + ko; dst = buf + 5120 + t2 * 8; }
            else if (arr == 2) { src = Wuh + gr * 1024 + 512 + ko; dst = buf + 7168 + t2 * 8; }
            else { src = Wul + gr * 1024 + 512 + ko; dst = buf + 9216 + t2 * 8; }
            gl_lds16(src, dst);
        }
    };
    __syncthreads();  // D reads done
    stageE(sm, 0);
    __syncthreads();
    for (int t = 0; t < 16; ++t) {
        u16* cur = sm + (t & 1) * 11264;
        if (t + 1 < 16) stageE(sm + ((t + 1) & 1) * 11264, (t + 1) * 32);
        int bo = nloc * 32 + ((ls ^ ((nloc >> 1) & 3)) << 3);
        bf16x8 gh8 = *(const bf16x8*)(cur + 3072 + bo);
        bf16x8 gl8 = *(const bf16x8*)(cur + 5120 + bo);
        bf16x8 uh8 = *(const bf16x8*)(cur + 7168 + bo);
        bf16x8 ul8 = *(const bf16x8*)(cur + 9216 + bo);
        for (int i = 0; i < nrf; ++i) {
            int row = 16 * (rf0 + i) + lr;
            int ao = row * 32 + ((ls ^ ((row >> 1) & 3)) << 3);
            bf16x8 qh8 = *(const bf16x8*)(cur + ao);
            bf16x8 ql8 = *(const bf16x8*)(cur + 1536 + ao);
            accg[i] = mfma16(qh8, gh8, accg[i]);
            accg[i] = mfma16(qh8, gl8, accg[i]);
            accg[i] = mfma16(ql8, gh8, accg[i]);
            accu[i] = mfma16(qh8, uh8, accu[i]);
            accu[i] = mfma16(qh8, ul8, accu[i]);
            accu[i] = mfma16(ql8, uh8, accu[i]);
        }
        __syncthreads();
    }

    // ---- Epilogue: q update ----
    for (int i = 0; i < nrf; ++i)
#pragma unroll
        for (int r = 0; r < 4; ++r) {
            int row = 16 * (rf0 + i) + 4 * ls + r;
            int col = nglob + cfD * 16 + lr;
            size_t o = (qrow0 + row) * DD + col;
            float gpre = accg[i][r] + CgL[(size_t)b * DD + col];
            float upre = accu[i][r] + bu[col];
            float g = 1.0f / (1.0f + __expf(-gpre));
            float u = tanhf(upre);
            float qv = bf2f(qhp[o]) + bf2f(qlp[o]);
            float qo = g * qv + (1.0f - g) * u;
            u16 hh = bf16h(qo);
            qoh[o] = hh;
            qol[o] = bf16h(qo - bf2f(hh));
        }
}

// ---------------------------------------------------------------------------
__global__ __launch_bounds__(256) void final_kernel(const float* __restrict__ fuse_last,
                                                    const float* __restrict__ ce,
                                                    const float* __restrict__ W_cls,
                                                    const float* __restrict__ b_cls,
                                                    const float* __restrict__ loss_acc,
                                                    float* __restrict__ out) {
    int b = blockIdx.x;
    int t = threadIdx.x;
    int w = t >> 6, lane = t & 63;
    __shared__ float invn[CC];
    __shared__ float img[CC];
    const float* fb = fuse_last + (size_t)b * CC * DD;
    for (int c = w; c < CC; c += 4) {
        const float* fr = fb + (size_t)c * DD + lane * 8;
        float4 a0 = *(const float4*)fr;
        float4 a1 = *(const float4*)(fr + 4);
        float ss = a0.x * a0.x + a0.y * a0.y + a0.z * a0.z + a0.w * a0.w +
                   a1.x * a1.x + a1.y * a1.y + a1.z * a1.z + a1.w * a1.w;
#pragma unroll
        for (int off = 32; off > 0; off >>= 1) ss += __shfl_xor(ss, off);
        if (lane == 0) invn[c] = 1.0f / fmaxf(sqrtf(ss), 1e-12f);
    }
    __syncthreads();
    for (int g = w; g < CC; g += 4) {
        int k = g / 6;
        const float* ar = ce + (size_t)g * DD + lane * 8;
        float4 c0 = *(const float4*)ar;
        float4 c1 = *(const float4*)(ar + 4);
        float av[8] = {c0.x, c0.y, c0.z, c0.w, c1.x, c1.y, c1.z, c1.w};
        float accp = 0.0f;
        for (int p = 0; p < 6; ++p) {
            int row = k * 6 + p;
            const float* fr = fb + (size_t)row * DD + lane * 8;
            float4 f0 = *(const float4*)fr;
            float4 f1 = *(const float4*)(fr + 4);
            float fv[8] = {f0.x, f0.y, f0.z, f0.w, f1.x, f1.y, f1.z, f1.w};
            float d = 0.0f;
#pragma unroll
            for (int j = 0; j < 8; ++j) d += fv[j] * av[j];
            accp += d * invn[row];
        }
#pragma unroll
        for (int off = 32; off > 0; off >>= 1) accp += __shfl_xor(accp, off);
        if (lane == 0) img[g] = accp * (100.0f / 6.0f);
    }
    __syncthreads();
    if (t < CC) out[BB * 7 + b * CC + t] = img[t];
    if (t < 7) {
        float sacc = b_cls[t];
        for (int c = 0; c < CC; ++c) sacc += img[c] * W_cls[t * CC + c];
        out[b * 7 + t] = sacc;
    }
    if (b == 0 && t == 0) out[BB * 7 + BB * CC] = loss_acc[0] * (1.0f / LOSS_DEN);
}

// ---------------------------------------------------------------------------
extern "C" void kernel_launch(void* const* d_in, const int* in_sizes, int n_in,
                              void* d_out, int out_size, void* d_ws, size_t ws_size,
                              hipStream_t stream) {
    const float* feats = (const float*)d_in[0];
    const float* ce = (const float*)d_in[1];
    const float* W_lin = (const float*)d_in[2];
    const float* b_lin = (const float*)d_in[3];
    const float* W_proj = (const float*)d_in[4];
    const float* W_gate = (const float*)d_in[5];
    const float* b_gate = (const float*)d_in[6];
    const float* W_upd = (const float*)d_in[7];
    const float* b_upd = (const float*)d_in[8];
    const float* W_cls = (const float*)d_in[9];
    const float* b_cls = (const float*)d_in[10];
    float* out = (float*)d_out;

    char* base = (char*)d_ws;
    size_t off = 0;
    auto alloc = [&](size_t bytes) -> char* {
        char* r = base + off;
        off += (bytes + 255) & ~(size_t)255;
        return r;
    };
    u16* Xh = (u16*)alloc((size_t)LL * BB * VV * DV * 2);
    u16* Xl = (u16*)alloc((size_t)LL * BB * VV * DV * 2);
    u16* vth = (u16*)alloc((size_t)LL * BB * VV * DD * 2);
    u16* vtl = (u16*)alloc((size_t)LL * BB * VV * DD * 2);
    u16* vtTh = (u16*)alloc((size_t)LL * BB * 512 * 64 * 2);
    u16* vtTl = (u16*)alloc((size_t)LL * BB * 512 * 64 * 2);
    float* ctx = (float*)alloc((size_t)LL * BB * DD * 4);
    float* Cg = (float*)alloc((size_t)LL * BB * DD * 4);
    float* fbuf0 = (float*)alloc((size_t)BB * CC * DD * 4);
    float* fbuf1 = (float*)alloc((size_t)BB * CC * DD * 4);
    float* loss = (float*)alloc(256);
    u16* Wlh = (u16*)alloc((size_t)NLW * 2);
    u16* Wll = (u16*)alloc((size_t)NLW * 2);
    u16* Wgh = (u16*)alloc((size_t)NGW * 2);
    u16* Wgl = (u16*)alloc((size_t)NGW * 2);
    u16* Wuh = (u16*)alloc((size_t)NUW * 2);
    u16* Wul = (u16*)alloc((size_t)NUW * 2);
    u16* qah = (u16*)alloc((size_t)BB * CC * DD * 2);
    u16* qal = (u16*)alloc((size_t)BB * CC * DD * 2);
    u16* qbh = (u16*)alloc((size_t)BB * CC * DD * 2);
    u16* qbl = (u16*)alloc((size_t)BB * CC * DD * 2);
    u16* qph[2] = {qah, qbh};
    u16* qpl[2] = {qal, qbl};

    // ---- precompute ----
    pool_split<<<LL * BB * VV, 256, 0, stream>>>(feats, Xh, Xl);
    wsplit_all<<<(NLW + NGW + NUW) / 256, 256, 0, stream>>>(W_lin, W_gate, W_upd, Wlh, Wll, Wgh, Wgl, Wuh, Wul);
    {
        dim3 g(LL * BB / 64, DD / 64);
        gemm_f32<<<g, 256, 0, stream>>>(feats, SS * DV, W_proj, DV, DV, nullptr, ctx);
        gemm_f32<<<g, 256, 0, stream>>>(ctx, DD, W_gate + 1024, 1536, DD, b_gate, Cg);
    }
    init_q_loss<<<(BB * CC * DD) / 256, 256, 0, stream>>>(ce, qah, qal, loss);
    {
        dim3 g(147, 8);
        vt_gemm<<<g, 256, 0, stream>>>(Xh, Xl, Wlh, Wll, b_lin, vth, vtl);
    }
    vtT_kernel<<<LL * BB, 256, 0, stream>>>(vth, vtl, vtTh, vtTl);

    // ---- 12-layer scan: one kernel per layer ----
    int qc = 0;
    for (int l = 0; l < LL; ++l) {
        float* fcur = (l & 1) ? fbuf1 : fbuf0;
        const float* fprev = (l & 1) ? fbuf0 : fbuf1;
        int last = (l == LL - 1) ? 1 : 0;
        int grid = last ? BB : BB * 8;
        layer_fused<<<grid, 512, 0, stream>>>(
            qph[qc], qpl[qc],
            vth + (size_t)l * BB * VV * DD, vtl + (size_t)l * BB * VV * DD,
            vtTh + (size_t)l * BB * 512 * 64, vtTl + (size_t)l * BB * 512 * 64,
            Wgh, Wgl, Wuh, Wul,
            Cg + (size_t)l * BB * DD, b_upd,
            fcur, fprev, loss, l > 0 ? 1 : 0, last,
            qph[qc ^ 1], qpl[qc ^ 1]);
        if (!last) qc ^= 1;
    }

    final_kernel<<<BB, 256, 0, stream>>>((LL - 1) & 1 ? fbuf1 : fbuf0, ce, W_cls, b_cls, loss, out);
}